// Round 13
// baseline (3083.292 us; speedup 1.0000x reference)
//
#include <hip/hip_runtime.h>
#include <hip/hip_bf16.h>

#define TSTEPS 20
#define SMEM_BYTES 131072

typedef __bf16 bf16x8 __attribute__((ext_vector_type(8)));
typedef float f32x4 __attribute__((ext_vector_type(4)));
typedef unsigned short u16;

__device__ __forceinline__ u16 f2bf(float f) {
  unsigned u = __builtin_bit_cast(unsigned, f);
  u = (u + 0x7FFFu + ((u >> 16) & 1u)) >> 16;  // RNE
  return (u16)u;
}
__device__ __forceinline__ float rcp_(float v) { return __builtin_amdgcn_rcpf(v); }
__device__ __forceinline__ float sig_(float v) { return rcp_(1.f + __expf(-v)); }
__device__ __forceinline__ float tanh_(float v) { return 1.f - 2.f * rcp_(1.f + __expf(2.f * v)); }

#define MFMA16(a, b, c) __builtin_amdgcn_mfma_f32_16x16x32_bf16((a), (b), (c), 0, 0, 0)
#define BAR() asm volatile("s_barrier" ::: "memory")
#define WAITV(n) asm volatile("s_waitcnt vmcnt(" #n ")" ::: "memory")

__device__ __forceinline__ void gload16(const u16* g, u16* lds) {
#if defined(__HIP_DEVICE_COMPILE__)
  __builtin_amdgcn_global_load_lds(
      (const __attribute__((address_space(1))) unsigned*)g,
      (__attribute__((address_space(3))) unsigned*)lds, 16, 0, 0);
#endif
}

// ---------------- prep kernels ----------------
// permuted Whh: p = s*256 + w*64 + f*16 + j  <-  orig row f*512 + s*64 + w*16 + j
__global__ void convert_whh_p(const float* __restrict__ w, u16* __restrict__ d) {
  int p = blockIdx.x;
  int k = threadIdx.x;
  int j = p & 15, f = (p >> 4) & 3, wg = (p >> 6) & 3, s = p >> 8;
  int orig = (f << 9) + (s << 6) + (wg << 4) + j;
  d[p * 512 + k] = f2bf(w[orig * 512 + k]);
}

// fc1w -> frag-major (see R11): slab (s,tf) is a contiguous 128 KB block.
__global__ void fc1p_prep(const float* __restrict__ w, u16* __restrict__ d) {
  int id = blockIdx.x * blockDim.x + threadIdx.x;  // 1310720
  int jl = id & 15, t1 = id >> 4;
  int kg = t1 & 3, t2 = t1 >> 2;
  int jf = t2 & 1, t3 = t2 >> 1;
  int Fwn = t3 & 1, t4 = t3 >> 1;
  int kk2 = t4 & 31, t5 = t4 >> 5;
  int tf = t5 % 20, s = t5 / 20;
  int j = s * 64 + Fwn * 32 + jf * 16 + jl;
  int k = kk2 * 32 + kg * 8;
  const float* src = w + j * 20480 + (k >> 9) * 10240 + tf * 512 + (k & 511);
  float4 v0 = *reinterpret_cast<const float4*>(src);
  float4 v1 = *reinterpret_cast<const float4*>(src + 4);
  u16* dst = d + id * 8;
  dst[0] = f2bf(v0.x); dst[1] = f2bf(v0.y); dst[2] = f2bf(v0.z); dst[3] = f2bf(v0.w);
  dst[4] = f2bf(v1.x); dst[5] = f2bf(v1.y); dst[6] = f2bf(v1.z); dst[7] = f2bf(v1.w);
}

// h -> bf16; c0 -> per-thread-linear; zero barrier counters
__global__ void init_state(const float* __restrict__ h0, const float* __restrict__ c0,
                           u16* __restrict__ hbf, float* __restrict__ cws,
                           int* __restrict__ cnt, int nh) {
  int i = blockIdx.x * blockDim.x + threadIdx.x;
  if (i < nh) {
    hbf[i] = f2bf(h0[i]);
    int r = i & 3, mt = (i >> 2) & 7, lane = (i >> 5) & 63, wid = (i >> 11) & 7, bid = i >> 14;
    int s = (bid >> 3) & 7, nb = (bid & 7) * 4 + (bid >> 6);
    int wm = wid >> 2, wn = wid & 3;
    int jl = lane & 15, kg = lane >> 4;
    int n = nb * 256 + wm * 128 + mt * 16 + kg * 4 + r;
    int u = s * 64 + wn * 16 + jl;
    cws[i] = c0[n * 512 + u];
  }
  if (i < 1024) cnt[i] = 0;
}

// ---------------- persistent fused kernel ----------------
// 256 blocks x 512 thr, 1 block/CU (128 KB LDS forces it; grid == #CUs so all
// blocks co-resident -> per-group spin barriers cannot deadlock).
// Group gg = (bid&7)*4 + (bid>>6) owns n-rows [gg*256, +256); its 8 slab-blocks
// share bid%8 (same XCD under round-robin dispatch; correctness holds anyway
// via device-scope atomics/fences). Per iteration i: LSTM(i) fused with
// FC1(i-1) sharing the staged A tiles (R12 scheme); i==20 = FC1(19) tail.
// c-state and FC1 accumulator live in registers for the whole run.
__global__ __launch_bounds__(512, 1) void lstm_persist(
    const u16* __restrict__ Wp,     // [2048][512] perm bf16
    const float* __restrict__ Wih,  // [2048][2]
    const float* __restrict__ bih, const float* __restrict__ bhh,
    const float* __restrict__ x,    // [8192][20][2] f32
    u16* __restrict__ hb0,          // h(even)
    u16* __restrict__ hb1,          // h(odd)
    float* __restrict__ cws,        // c-state per-thread-linear (init only)
    const u16* __restrict__ fc1p,   // frag-major fc1w
    float* __restrict__ faccg,      // [4096][512] f32 out
    int* __restrict__ cnt) {
  extern __shared__ char S[];       // 128 KB: p*65536 + {A:0..32K, B:32K..64K}

  const int tid = threadIdx.x;
  const int lane = tid & 63, wid = tid >> 6;
  const int jl = lane & 15, kg = lane >> 4;
  const int bid = blockIdx.x;
  const int s = (bid >> 3) & 7;
  const int nb = (bid & 7) * 4 + (bid >> 6);
  const int n0 = nb * 256;
  const int srow = tid >> 3;
  const int sw = (tid & 7) ^ (srow & 7);

  const int wm = wid >> 2, wn = wid & 3;        // LSTM wave map 2M x 4N
  const int Fwm = wid >> 1, Fwn = wid & 1;      // FC1 wave map 4M x 2N
  const int u = s * 64 + wn * 16 + jl;
  const int swz0 = (kg ^ (jl & 7)) * 16;
  const int swz1 = ((4 + kg) ^ (jl & 7)) * 16;
  const int aB0 = wm * 16384 + jl * 128 + swz0;
  const int aB1 = wm * 16384 + jl * 128 + swz1;
  const int bB0 = 32768 + wn * 8192 + jl * 128 + swz0;
  const int bB1 = 32768 + wn * 8192 + jl * 128 + swz1;
  const u16* srcB = Wp + (s * 256 + srow) * 512 + sw * 8;
  int* gcnt = cnt + ((bid & 7) * 4 + (bid >> 6)) * 32;

  // ---- persistent per-thread state ----
  float eb[4], w0v[4], w1v[4];
#pragma unroll
  for (int f = 0; f < 4; ++f) {
    int j = f * 512 + u;
    eb[f] = bih[j] + bhh[j];
    w0v[f] = Wih[j * 2 + 0];
    w1v[f] = Wih[j * 2 + 1];
  }
  float* cbase = cws + ((bid * 8 + wid) * 64 + lane) * 32;
  f32x4 creg[8];
#pragma unroll
  for (int mt = 0; mt < 8; ++mt) creg[mt] = *reinterpret_cast<f32x4*>(cbase + mt * 4);
  f32x4 fa[2][2];
#pragma unroll
  for (int a = 0; a < 2; ++a)
#pragma unroll
    for (int b = 0; b < 2; ++b) fa[a][b] = (f32x4){0.f, 0.f, 0.f, 0.f};

#define LSTAGE(kt, p)                                                              \
  do {                                                                             \
    _Pragma("unroll") for (int q = 0; q < 4; ++q) {                                \
      gload16(srcA + q * 32768 + (kt) * 64, (u16*)(S + (p) * 65536 + q * 8192 + wid * 1024)); \
      gload16(srcB + q * 32768 + (kt) * 64, (u16*)(S + (p) * 65536 + 32768 + q * 8192 + wid * 1024)); \
    }                                                                              \
  } while (0)
#define LCOMP(p)                                                                   \
  do {                                                                             \
    bf16x8 a0[8], b0[4];                                                           \
    _Pragma("unroll") for (int mt = 0; mt < 8; ++mt)                               \
        a0[mt] = *reinterpret_cast<const bf16x8*>(S + (p) * 65536 + aB0 + mt * 2048); \
    _Pragma("unroll") for (int f = 0; f < 4; ++f)                                  \
        b0[f] = *reinterpret_cast<const bf16x8*>(S + (p) * 65536 + bB0 + f * 2048); \
    _Pragma("unroll") for (int mt = 0; mt < 8; ++mt)                               \
      _Pragma("unroll") for (int f = 0; f < 4; ++f)                                \
        acc[mt][f] = MFMA16(a0[mt], b0[f], acc[mt][f]);                            \
    _Pragma("unroll") for (int mt = 0; mt < 8; ++mt)                               \
        a0[mt] = *reinterpret_cast<const bf16x8*>(S + (p) * 65536 + aB1 + mt * 2048); \
    _Pragma("unroll") for (int f = 0; f < 4; ++f)                                  \
        b0[f] = *reinterpret_cast<const bf16x8*>(S + (p) * 65536 + bB1 + f * 2048); \
    _Pragma("unroll") for (int mt = 0; mt < 8; ++mt)                               \
      _Pragma("unroll") for (int f = 0; f < 4; ++f)                                \
        acc[mt][f] = MFMA16(a0[mt], b0[f], acc[mt][f]);                            \
  } while (0)
#define FC1COMP(P)                                                                 \
  do {                                                                             \
    _Pragma("unroll") for (int kk = 0; kk < 2; ++kk) {                             \
      _Pragma("unroll") for (int mf = 0; mf < 2; ++mf) {                           \
        const int er = Fwm * 64 + mf * 32 + 2 * jl;                                \
        bf16x8 ae = *reinterpret_cast<const bf16x8*>(                              \
            S + (P) * 65536 + er * 128 + (((kk * 4) + kg) ^ (er & 7)) * 16);       \
        bf16x8 ao = *reinterpret_cast<const bf16x8*>(                              \
            S + (P) * 65536 + (er + 1) * 128 + (((kk * 4) + kg) ^ ((er + 1) & 7)) * 16); \
        _Pragma("unroll") for (int jf = 0; jf < 2; ++jf) {                         \
          fa[mf][jf] = MFMA16(ae, fbe[jf][kk], fa[mf][jf]);                        \
          fa[mf][jf] = MFMA16(ao, fbo[jf][kk], fa[mf][jf]);                        \
        }                                                                          \
      }                                                                            \
    }                                                                              \
  } while (0)

#pragma unroll 1
  for (int i = 0; i <= TSTEPS; ++i) {
    const u16* hin = (i & 1) ? hb1 : hb0;
    u16* hnxt = (i & 1) ? hb0 : hb1;
    const u16* srcA = hin + (n0 + srow) * 512 + sw * 8;
    const u16* fbl = (i > 0) ? (fc1p + (s * 20 + (i - 1)) * 65536 + Fwn * 1024 + kg * 128 + jl * 8)
                             : fc1p;

    if (i < TSTEPS) {
      // ================= LSTM(i) + FC1(i-1) fused 8-phase loop =================
      f32x4 acc[8][4];
#pragma unroll
      for (int mt = 0; mt < 8; ++mt)
#pragma unroll
        for (int f = 0; f < 4; ++f) acc[mt][f] = (f32x4){0.f, 0.f, 0.f, 0.f};

      LSTAGE(0, 0);  // prologue: tile0 -> p0 (8 loads)
#pragma unroll
      for (int kt = 0; kt < 8; ++kt) {
        bf16x8 fbe[2][2], fbo[2][2];
        if (i > 0) {
#pragma unroll
          for (int jf = 0; jf < 2; ++jf)
#pragma unroll
            for (int kk = 0; kk < 2; ++kk) {
              fbe[jf][kk] = *reinterpret_cast<const bf16x8*>(fbl + (2 * kt + kk) * 2048 + jf * 512);
              fbo[jf][kk] = *reinterpret_cast<const bf16x8*>(fbl + (2 * kt + 16 + kk) * 2048 + jf * 512);
            }
        }
        if (kt < 7) {
          if ((kt + 1) & 1) LSTAGE(kt + 1, 1); else LSTAGE(kt + 1, 0);
          if (i > 0) { WAITV(16); } else { WAITV(8); }   // drain tile kt only
        } else {
          if (i > 0) { WAITV(8); } else { WAITV(0); }    // fb frags may stay in flight
        }
        BAR();
        __builtin_amdgcn_s_setprio(1);
        if (kt & 1) LCOMP(1); else LCOMP(0);
        __builtin_amdgcn_s_setprio(0);
        if (i > 0) {
          if (kt & 1) FC1COMP(1); else FC1COMP(0);
        }
        BAR();
      }

      // ---- scalar epilogue: aug terms + activations; c stays in regs ----
#pragma unroll
      for (int mt = 0; mt < 8; ++mt) {
        const int nbase = n0 + wm * 128 + mt * 16 + kg * 4;
        f32x4 cv = creg[mt];
        f32x4 cn;
        float hn[4];
#pragma unroll
        for (int r = 0; r < 4; ++r) {
          float2 xv = *reinterpret_cast<const float2*>(x + (nbase + r) * 40 + i * 2);
          float gi = acc[mt][0][r] + eb[0] + xv.x * w0v[0] + xv.y * w1v[0];
          float gf = acc[mt][1][r] + eb[1] + xv.x * w0v[1] + xv.y * w1v[1];
          float gg = acc[mt][2][r] + eb[2] + xv.x * w0v[2] + xv.y * w1v[2];
          float go = acc[mt][3][r] + eb[3] + xv.x * w0v[3] + xv.y * w1v[3];
          float iv = sig_(gi), fv = sig_(gf), gv = tanh_(gg), ov = sig_(go);
          float c2 = fv * cv[r] + iv * gv;
          cn[r] = c2;
          hn[r] = ov * tanh_(c2);
        }
        creg[mt] = cn;
#pragma unroll
        for (int r = 0; r < 4; ++r)
          hnxt[(nbase + r) * 512 + u] = f2bf(hn[r]);
      }

      // ---- per-group barrier: publish h(i+1) ----
      __syncthreads();
      if (tid == 0) {
        __threadfence();
        __hip_atomic_fetch_add(gcnt, 1, __ATOMIC_ACQ_REL, __HIP_MEMORY_SCOPE_AGENT);
        const int tgt = 8 * (i + 1);
        while (__hip_atomic_load(gcnt, __ATOMIC_ACQUIRE, __HIP_MEMORY_SCOPE_AGENT) < tgt)
          __builtin_amdgcn_s_sleep(2);
      }
      __syncthreads();
      __threadfence();
    } else {
      // ================= tail: FC1(19), A = h(20) self-staged =================
#pragma unroll
      for (int q = 0; q < 4; ++q)
        gload16(srcA + q * 32768, (u16*)(S + q * 8192 + wid * 1024));
#pragma unroll
      for (int kt = 0; kt < 8; ++kt) {
        bf16x8 fbe[2][2], fbo[2][2];
#pragma unroll
        for (int jf = 0; jf < 2; ++jf)
#pragma unroll
          for (int kk = 0; kk < 2; ++kk) {
            fbe[jf][kk] = *reinterpret_cast<const bf16x8*>(fbl + (2 * kt + kk) * 2048 + jf * 512);
            fbo[jf][kk] = *reinterpret_cast<const bf16x8*>(fbl + (2 * kt + 16 + kk) * 2048 + jf * 512);
          }
        if (kt < 7) {
          const int pn = (kt + 1) & 1;
#pragma unroll
          for (int q = 0; q < 4; ++q)
            gload16(srcA + q * 32768 + (kt + 1) * 64, (u16*)(S + pn * 65536 + q * 8192 + wid * 1024));
          WAITV(12);
        } else {
          WAITV(8);
        }
        BAR();
        if (kt & 1) FC1COMP(1); else FC1COMP(0);
        BAR();
      }
    }
  }

  // ---- final: write FC1 accumulator (no RMW; poison-safe full overwrite) ----
  const int Fm0 = nb * 128, Fj0 = s * 64;
#pragma unroll
  for (int mf = 0; mf < 2; ++mf)
#pragma unroll
    for (int jf = 0; jf < 2; ++jf) {
      int j = Fj0 + Fwn * 32 + jf * 16 + jl;
#pragma unroll
      for (int r = 0; r < 4; ++r) {
        int m = Fm0 + Fwm * 32 + mf * 16 + kg * 4 + r;
        faccg[m * 512 + j] = fa[mf][jf][r];
      }
    }
}

// ---------------- head: relu(facc + b1) @ fc2^T + b2, sigmoid ----------------
__global__ __launch_bounds__(256) void head_kernel(
    const float* __restrict__ acc, const float* __restrict__ fc1b,
    const float* __restrict__ fc2w, const float* __restrict__ fc2b,
    float* __restrict__ out) {
  int lane = threadIdx.x & 63;
  int row = blockIdx.x * 4 + (threadIdx.x >> 6);
  float sum = 0.f;
#pragma unroll
  for (int j = lane; j < 512; j += 64)
    sum += fmaxf(acc[row * 512 + j] + fc1b[j], 0.f) * fc2w[j];
#pragma unroll
  for (int off = 32; off; off >>= 1) sum += __shfl_down(sum, off);
  if (lane == 0) out[row] = sig_(sum + fc2b[0]);
}

extern "C" void kernel_launch(void* const* d_in, const int* in_sizes, int n_in,
                              void* d_out, int out_size, void* d_ws, size_t ws_size,
                              hipStream_t stream) {
  const float* x = (const float*)d_in[0];
  const float* h0 = (const float*)d_in[2];
  const float* c0 = (const float*)d_in[3];
  const float* Wih = (const float*)d_in[4];
  const float* Whh = (const float*)d_in[5];
  const float* bih = (const float*)d_in[6];
  const float* bhh = (const float*)d_in[7];
  const float* fc1w = (const float*)d_in[8];
  const float* fc1b = (const float*)d_in[9];
  const float* fc2w = (const float*)d_in[10];
  const float* fc2b = (const float*)d_in[11];
  float* out = (float*)d_out;

  char* ws = (char*)d_ws;
  const size_t MB = 1 << 20;
  u16* Wp = (u16*)(ws);                  //  2 MB perm Whh
  u16* fc1p = (u16*)(ws + 2 * MB);       // 20 MB frag-major fc1w
  u16* hbf0 = (u16*)(ws + 22 * MB);      //  8 MB
  u16* hbf1 = (u16*)(ws + 30 * MB);      //  8 MB
  float* cws = (float*)(ws + 38 * MB);   // 16 MB per-thread-linear c
  float* facc = (float*)(ws + 54 * MB);  //  8 MB
  int* cnt = (int*)(ws + 62 * MB);       //  4 KB barrier counters

  (void)hipFuncSetAttribute(reinterpret_cast<const void*>(lstm_persist),
                            hipFuncAttributeMaxDynamicSharedMemorySize, SMEM_BYTES);

  convert_whh_p<<<2048, 512, 0, stream>>>(Whh, Wp);
  fc1p_prep<<<2560, 512, 0, stream>>>(fc1w, fc1p);
  init_state<<<16384, 256, 0, stream>>>(h0, c0, hbf0, cws, cnt, 8192 * 512);

  lstm_persist<<<256, 512, SMEM_BYTES, stream>>>(
      Wp, Wih, bih, bhh, x, hbf0, hbf1, cws, fc1p, facc, cnt);
  head_kernel<<<1024, 256, 0, stream>>>(facc, fc1b, fc2w, fc2b, out);
}

// Round 14
// 611.070 us; speedup vs baseline: 5.0457x; 5.0457x over previous
//
#include <hip/hip_runtime.h>
#include <hip/hip_bf16.h>

#define TSTEPS 20
#define SMEM_BYTES 131072

typedef __bf16 bf16x8 __attribute__((ext_vector_type(8)));
typedef float f32x4 __attribute__((ext_vector_type(4)));
typedef _Float16 f16x4 __attribute__((ext_vector_type(4)));
typedef unsigned short u16;

__device__ __forceinline__ u16 f2bf(float f) {
  unsigned u = __builtin_bit_cast(unsigned, f);
  u = (u + 0x7FFFu + ((u >> 16) & 1u)) >> 16;  // RNE
  return (u16)u;
}
__device__ __forceinline__ float rcp_(float v) { return __builtin_amdgcn_rcpf(v); }
__device__ __forceinline__ float sig_(float v) { return rcp_(1.f + __expf(-v)); }
__device__ __forceinline__ float tanh_(float v) { return 1.f - 2.f * rcp_(1.f + __expf(2.f * v)); }

#define MFMA16(a, b, c) __builtin_amdgcn_mfma_f32_16x16x32_bf16((a), (b), (c), 0, 0, 0)
#define BAR() asm volatile("s_barrier" ::: "memory")
#define WAITV(n) asm volatile("s_waitcnt vmcnt(" #n ")" ::: "memory")
#define WAITLG() asm volatile("s_waitcnt lgkmcnt(0)" ::: "memory")

__device__ __forceinline__ void gload16(const u16* g, u16* lds) {
#if defined(__HIP_DEVICE_COMPILE__)
  __builtin_amdgcn_global_load_lds(
      (const __attribute__((address_space(1))) unsigned*)g,
      (__attribute__((address_space(3))) unsigned*)lds, 16, 0, 0);
#endif
}

// ---------------- prep kernels ----------------
__global__ void convert_f32_bf16(const float* __restrict__ s, u16* __restrict__ d, int n) {
  int i = (blockIdx.x * blockDim.x + threadIdx.x) * 4;
  if (i + 3 < n) {
    float4 v = *reinterpret_cast<const float4*>(s + i);
    ushort4 o;
    o.x = f2bf(v.x); o.y = f2bf(v.y); o.z = f2bf(v.z); o.w = f2bf(v.w);
    *reinterpret_cast<ushort4*>(d + i) = o;
  }
}

// permuted Whh: p = s*256 + w*64 + f*16 + j  <-  orig row f*512 + s*64 + w*16 + j
__global__ void convert_whh_p(const float* __restrict__ w, u16* __restrict__ d) {
  int p = blockIdx.x;
  int k = threadIdx.x;
  int j = p & 15, f = (p >> 4) & 3, wg = (p >> 6) & 3, s = p >> 8;
  int orig = (f << 9) + (s << 6) + (wg << 4) + j;
  d[p * 512 + k] = f2bf(w[orig * 512 + k]);
}

// augmented-B: Bx[p][0..31] = [Wih[o][0], Wih[o][1], bih[o]+bhh[o], 0...]
__global__ void bx_prep(const float* __restrict__ Wih, const float* __restrict__ bih,
                        const float* __restrict__ bhh, u16* __restrict__ Bx) {
  int p = blockIdx.x * blockDim.x + threadIdx.x;
  if (p >= 2048) return;
  int j = p & 15, f = (p >> 4) & 3, wg = (p >> 6) & 3, s = p >> 8;
  int o = (f << 9) + (s << 6) + (wg << 4) + j;
  u16* row = Bx + p * 32;
  row[0] = f2bf(Wih[o * 2 + 0]);
  row[1] = f2bf(Wih[o * 2 + 1]);
  row[2] = f2bf(bih[o] + bhh[o]);
#pragma unroll
  for (int k = 3; k < 32; ++k) row[k] = 0;
}

// h -> bf16; c0 -> fp16 per-thread-linear (epilogue layout); facc -> 0
__global__ void init_state(const float* __restrict__ h0, const float* __restrict__ c0,
                           u16* __restrict__ hbf, _Float16* __restrict__ cws,
                           float* __restrict__ facc, int nh, int nacc) {
  int i = blockIdx.x * blockDim.x + threadIdx.x;
  if (i < nh) {
    hbf[i] = f2bf(h0[i]);
    int r = i & 3, mt = (i >> 2) & 7, lane = (i >> 5) & 63, wid = (i >> 11) & 7, bid = i >> 14;
    int s = (bid >> 3) & 7, nb = (bid & 7) * 4 + (bid >> 6);
    int wm = wid >> 2, wn = wid & 3;
    int jl = lane & 15, kg = lane >> 4;
    int n = nb * 256 + wm * 128 + mt * 16 + kg * 4 + r;
    int u = s * 64 + wn * 16 + jl;
    cws[i] = (_Float16)c0[n * 512 + u];
  }
  if (i < nacc) facc[i] = 0.f;
}

// ---------------- fused step kernel: 256 blocks x 512 threads, 1 block/CU ----
// LSTM step t: block tile 256n x 256pc (4 gates x 64 u), K=512+aug32, BK=64.
// FC1 (t-1): block tile 128m x 64j, K=1024, BK=128 (8 phases), A = hin rows.
// XCD-bijective: bid&7 = xcd, nb = (bid&7)*4 + (bid>>6), s = (bid>>3)&7.
// K-loop ring: stage(k+1) issued in iter k; counted WAITV leaves it in flight
// across the whole compute(k) phase.
__global__ __launch_bounds__(512, 1) void step256(
    const u16* __restrict__ Wp,     // [2048][512] perm bf16
    const u16* __restrict__ Bxg,    // [2048][32] aug B
    const float* __restrict__ x,    // [8192][20][2] f32
    const u16* __restrict__ hin,    // [8192][512] bf16 = h(t)
    u16* __restrict__ hout,         // h(t+1)
    _Float16* __restrict__ cws,     // c-state fp16 per-thread-linear
    const u16* __restrict__ fc1w,   // [512][20480] bf16
    float* __restrict__ facc,       // [4096][512] f32
    int t, int doLstm, int doFc1) {
  extern __shared__ char S[];       // 128 KB: p*65536 + {A:0..32K, B:32K..64K}

  const int tid = threadIdx.x;
  const int lane = tid & 63, wid = tid >> 6;
  const int jl = lane & 15, kg = lane >> 4;
  const int bid = blockIdx.x;
  const int s = (bid >> 3) & 7;
  const int nb = (bid & 7) * 4 + (bid >> 6);
  const int n0 = nb * 256;
  const int srow = tid >> 3;
  const int sw = (tid & 7) ^ (srow & 7);

  if (doLstm) {
    const int wm = wid >> 2, wn = wid & 3;
    const int u = s * 64 + wn * 16 + jl;
    const int swz0 = (kg ^ (jl & 7)) * 16;
    const int swz1 = ((4 + kg) ^ (jl & 7)) * 16;
    const int aB0 = wm * 16384 + jl * 128 + swz0;
    const int aB1 = wm * 16384 + jl * 128 + swz1;
    const int bB0 = 32768 + wn * 8192 + jl * 128 + swz0;
    const int bB1 = 32768 + wn * 8192 + jl * 128 + swz1;
    const u16* srcA = hin + (n0 + srow) * 512 + sw * 8;
    const u16* srcB = Wp + (s * 256 + srow) * 512 + sw * 8;

    f32x4 acc[8][4];
#pragma unroll
    for (int mt = 0; mt < 8; ++mt)
#pragma unroll
      for (int f = 0; f < 4; ++f) acc[mt][f] = (f32x4){0.f, 0.f, 0.f, 0.f};

    // ---- prologue: x load, Bx stage (->p0 B slot), tile0 stage (->p1) ----
    float2 xv = {0.f, 0.f};
    if (tid < 256) xv = *reinterpret_cast<const float2*>(x + (n0 + tid) * 40 + t * 2);
    {
      const int r0 = tid >> 2, ch = tid & 3;
      gload16(Bxg + (s * 256 + 0 * 128 + r0) * 32 + ch * 8, (u16*)(S + 32768 + 0 * 8192 + wid * 1024));
      gload16(Bxg + (s * 256 + 1 * 128 + r0) * 32 + ch * 8, (u16*)(S + 32768 + 1 * 8192 + wid * 1024));
    }
#pragma unroll
    for (int q = 0; q < 4; ++q) {
      gload16(srcA + q * 32768, (u16*)(S + 65536 + q * 8192 + wid * 1024));
      gload16(srcB + q * 32768, (u16*)(S + 65536 + 32768 + q * 8192 + wid * 1024));
    }
    // build Ax rows [x0,x1,1,0...] in p0 A slot
    if (tid < 256) {
      u16 row0[8] = {f2bf(xv.x), f2bf(xv.y), 0x3F80u, 0, 0, 0, 0, 0};
      *reinterpret_cast<uint4*>(S + tid * 64) = *reinterpret_cast<const uint4*>(row0);
      uint4 z = {0u, 0u, 0u, 0u};
      *reinterpret_cast<uint4*>(S + tid * 64 + 16) = z;
      *reinterpret_cast<uint4*>(S + tid * 64 + 32) = z;
      *reinterpret_cast<uint4*>(S + tid * 64 + 48) = z;
    }
    WAITLG();
    WAITV(8);   // Bx (+x) drained; tile0's 8 still in flight
    BAR();
    // ---- aug phase (K=32): gates += x@Wih^T + biases ----
    {
#pragma unroll
      for (int mt = 0; mt < 8; ++mt) {
        bf16x8 a = *reinterpret_cast<const bf16x8*>(S + (wm * 128 + mt * 16 + jl) * 64 + kg * 16);
#pragma unroll
        for (int f = 0; f < 4; ++f) {
          bf16x8 b = *reinterpret_cast<const bf16x8*>(S + 32768 + (wn * 64 + f * 16 + jl) * 64 + kg * 16);
          acc[mt][f] = MFMA16(a, b, acc[mt][f]);
        }
      }
    }
    BAR();

    // ---- main K-loop: 8 tiles, tile kt lives at parity !(kt&1) ----
#define LSTAGE(kt, p)                                                              \
  do {                                                                             \
    _Pragma("unroll") for (int q = 0; q < 4; ++q) {                                \
      gload16(srcA + q * 32768 + (kt) * 64, (u16*)(S + (p) * 65536 + q * 8192 + wid * 1024)); \
      gload16(srcB + q * 32768 + (kt) * 64, (u16*)(S + (p) * 65536 + 32768 + q * 8192 + wid * 1024)); \
    }                                                                              \
  } while (0)
#define LCOMP(p)                                                                   \
  do {                                                                             \
    bf16x8 a0[8], b0[4];                                                           \
    _Pragma("unroll") for (int mt = 0; mt < 8; ++mt)                               \
        a0[mt] = *reinterpret_cast<const bf16x8*>(S + (p) * 65536 + aB0 + mt * 2048); \
    _Pragma("unroll") for (int f = 0; f < 4; ++f)                                  \
        b0[f] = *reinterpret_cast<const bf16x8*>(S + (p) * 65536 + bB0 + f * 2048); \
    _Pragma("unroll") for (int mt = 0; mt < 8; ++mt)                               \
      _Pragma("unroll") for (int f = 0; f < 4; ++f)                                \
        acc[mt][f] = MFMA16(a0[mt], b0[f], acc[mt][f]);                            \
    _Pragma("unroll") for (int mt = 0; mt < 8; ++mt)                               \
        a0[mt] = *reinterpret_cast<const bf16x8*>(S + (p) * 65536 + aB1 + mt * 2048); \
    _Pragma("unroll") for (int f = 0; f < 4; ++f)                                  \
        b0[f] = *reinterpret_cast<const bf16x8*>(S + (p) * 65536 + bB1 + f * 2048); \
    _Pragma("unroll") for (int mt = 0; mt < 8; ++mt)                               \
      _Pragma("unroll") for (int f = 0; f < 4; ++f)                                \
        acc[mt][f] = MFMA16(a0[mt], b0[f], acc[mt][f]);                            \
  } while (0)

#pragma unroll
    for (int kt = 0; kt < 8; ++kt) {
      if (kt < 7) {
        if ((kt + 1) & 1) LSTAGE(kt + 1, 0); else LSTAGE(kt + 1, 1);
        WAITV(8);
      } else {
        WAITV(0);
      }
      BAR();
      if (kt & 1) LCOMP(0); else LCOMP(1);
      BAR();
    }

    // ---- activation epilogue: c fp16 per-thread-linear ----
    _Float16* cbase = cws + ((bid * 8 + wid) * 64 + lane) * 32;
#pragma unroll
    for (int mt = 0; mt < 8; ++mt) {
      f16x4 cv = *reinterpret_cast<f16x4*>(cbase + mt * 4);
      f16x4 cn;
      float hn[4];
#pragma unroll
      for (int r = 0; r < 4; ++r) {
        float iv = sig_(acc[mt][0][r]);
        float fv = sig_(acc[mt][1][r]);
        float gv = tanh_(acc[mt][2][r]);
        float ov = sig_(acc[mt][3][r]);
        float c2 = fv * (float)cv[r] + iv * gv;
        cn[r] = (_Float16)c2;
        hn[r] = ov * tanh_(c2);
      }
      *reinterpret_cast<f16x4*>(cbase + mt * 4) = cn;
#pragma unroll
      for (int r = 0; r < 4; ++r)
        hout[(n0 + wm * 128 + mt * 16 + kg * 4 + r) * 512 + u] = f2bf(hn[r]);
    }
  }

  if (doFc1) {
    // ========== FC1 for t-1: 128m x 64j, K=1024, BK=128, 8 phases ==========
    // LDS per parity p (48 KB at S+p*65536):
    //   A slab kh: + kh*16384 + m*128 (+swz chunk), m = 0..127
    //   B slab kh: + 32768 + kh*8192 + j*128, j = 0..63
    const int Fm0 = nb * 128, Fj0 = s * 64;
    const int Fwm = wid >> 1, Fwn = wid & 1;
    const int tf = t - 1;

    f32x4 fa[2][2];
#pragma unroll
    for (int a = 0; a < 2; ++a)
#pragma unroll
      for (int b = 0; b < 2; ++b) fa[a][b] = (f32x4){0.f, 0.f, 0.f, 0.f};

#define FSTAGE(kt, p)                                                              \
  do {                                                                             \
    const int an_ = (kt) >> 2, hb_ = ((kt) & 3) * 128;                             \
    _Pragma("unroll") for (int kh = 0; kh < 2; ++kh) {                             \
      _Pragma("unroll") for (int q = 0; q < 2; ++q)                                \
        gload16(hin + (2 * (Fm0 + q * 64 + srow) + an_) * 512 + hb_ + kh * 64 + sw * 8, \
                (u16*)(S + (p) * 65536 + kh * 16384 + q * 8192 + wid * 1024));     \
      gload16(fc1w + (Fj0 + srow) * 20480 + an_ * 10240 + tf * 512 + hb_ + kh * 64 + sw * 8, \
              (u16*)(S + (p) * 65536 + 32768 + kh * 8192 + wid * 1024));           \
    }                                                                              \
  } while (0)
#define FCOMP(p)                                                                   \
  do {                                                                             \
    _Pragma("unroll") for (int kk = 0; kk < 4; ++kk) {                             \
      const int kh_ = kk >> 1;                                                     \
      const int cs_ = (((kk & 1) * 4 + kg) ^ (jl & 7)) * 16;                       \
      bf16x8 af[2], bf[2];                                                         \
      _Pragma("unroll") for (int mf = 0; mf < 2; ++mf)                             \
          af[mf] = *reinterpret_cast<const bf16x8*>(                               \
              S + (p) * 65536 + kh_ * 16384 + (Fwm * 32 + mf * 16 + jl) * 128 + cs_); \
      _Pragma("unroll") for (int jf = 0; jf < 2; ++jf)                             \
          bf[jf] = *reinterpret_cast<const bf16x8*>(                               \
              S + (p) * 65536 + 32768 + kh_ * 8192 + (Fwn * 32 + jf * 16 + jl) * 128 + cs_); \
      _Pragma("unroll") for (int mf = 0; mf < 2; ++mf)                             \
        _Pragma("unroll") for (int jf = 0; jf < 2; ++jf)                           \
          fa[mf][jf] = MFMA16(af[mf], bf[jf], fa[mf][jf]);                         \
    }                                                                              \
  } while (0)

    FSTAGE(0, 1);
#pragma unroll
    for (int kt = 0; kt < 8; ++kt) {
      if (kt < 7) {
        if ((kt + 1) & 1) FSTAGE(kt + 1, 0); else FSTAGE(kt + 1, 1);
        WAITV(6);   // drains tile kt (oldest 6); tile kt+1 in flight
      } else {
        WAITV(0);
      }
      BAR();
      if (kt & 1) FCOMP(0); else FCOMP(1);
      BAR();
    }
#pragma unroll
    for (int mf = 0; mf < 2; ++mf)
#pragma unroll
      for (int jf = 0; jf < 2; ++jf) {
        int j = Fj0 + Fwn * 32 + jf * 16 + jl;
#pragma unroll
        for (int r = 0; r < 4; ++r) {
          int m = Fm0 + Fwm * 32 + mf * 16 + kg * 4 + r;
          facc[m * 512 + j] += fa[mf][jf][r];
        }
      }
  }
}

// ---------------- head: relu(facc + b1) @ fc2^T + b2, sigmoid ----------------
__global__ __launch_bounds__(256) void head_kernel(
    const float* __restrict__ acc, const float* __restrict__ fc1b,
    const float* __restrict__ fc2w, const float* __restrict__ fc2b,
    float* __restrict__ out) {
  int lane = threadIdx.x & 63;
  int row = blockIdx.x * 4 + (threadIdx.x >> 6);
  float sum = 0.f;
#pragma unroll
  for (int j = lane; j < 512; j += 64)
    sum += fmaxf(acc[row * 512 + j] + fc1b[j], 0.f) * fc2w[j];
#pragma unroll
  for (int off = 32; off; off >>= 1) sum += __shfl_down(sum, off);
  if (lane == 0) out[row] = 1.f / (1.f + __expf(-(sum + fc2b[0])));
}

extern "C" void kernel_launch(void* const* d_in, const int* in_sizes, int n_in,
                              void* d_out, int out_size, void* d_ws, size_t ws_size,
                              hipStream_t stream) {
  const float* x = (const float*)d_in[0];
  const float* h0 = (const float*)d_in[2];
  const float* c0 = (const float*)d_in[3];
  const float* Wih = (const float*)d_in[4];
  const float* Whh = (const float*)d_in[5];
  const float* bih = (const float*)d_in[6];
  const float* bhh = (const float*)d_in[7];
  const float* fc1w = (const float*)d_in[8];
  const float* fc1b = (const float*)d_in[9];
  const float* fc2w = (const float*)d_in[10];
  const float* fc2b = (const float*)d_in[11];
  float* out = (float*)d_out;

  char* ws = (char*)d_ws;
  const size_t MB = 1 << 20;
  u16* Wp = (u16*)(ws);                       //  2 MB perm Whh
  u16* fc1_bf = (u16*)(ws + 2 * MB);          // 20 MB bf16 fc1w
  u16* hbf0 = (u16*)(ws + 22 * MB);           //  8 MB
  u16* hbf1 = (u16*)(ws + 30 * MB);           //  8 MB
  _Float16* cws = (_Float16*)(ws + 38 * MB);  //  8 MB fp16 c (per-thread-linear)
  float* facc = (float*)(ws + 46 * MB);       //  8 MB
  u16* Bxg = (u16*)(ws + 54 * MB);            // 128 KB

  (void)hipFuncSetAttribute(reinterpret_cast<const void*>(step256),
                            hipFuncAttributeMaxDynamicSharedMemorySize, SMEM_BYTES);

  convert_whh_p<<<2048, 512, 0, stream>>>(Whh, Wp);
  bx_prep<<<8, 256, 0, stream>>>(Wih, bih, bhh, Bxg);
  convert_f32_bf16<<<10240, 256, 0, stream>>>(fc1w, fc1_bf, 512 * 20480);
  init_state<<<16384, 256, 0, stream>>>(h0, c0, hbf0, cws, facc, 8192 * 512, 4096 * 512);

  u16* hb[2] = {hbf0, hbf1};
  for (int t = 0; t <= TSTEPS; ++t) {
    step256<<<256, 512, SMEM_BYTES, stream>>>(
        Wp, Bxg, x, hb[t & 1], hb[(t + 1) & 1], cws, fc1_bf, facc,
        t, t < TSTEPS ? 1 : 0, t > 0 ? 1 : 0);
  }
  head_kernel<<<1024, 256, 0, stream>>>(facc, fc1b, fc2w, fc2b, out);
}

// Round 15
// 594.844 us; speedup vs baseline: 5.1834x; 1.0273x over previous
//
#include <hip/hip_runtime.h>
#include <hip/hip_bf16.h>

#define TSTEPS 20
#define SMEM_BYTES 131072

typedef __bf16 bf16x8 __attribute__((ext_vector_type(8)));
typedef float f32x4 __attribute__((ext_vector_type(4)));
typedef _Float16 f16x4 __attribute__((ext_vector_type(4)));
typedef unsigned short u16;

__device__ __forceinline__ u16 f2bf(float f) {
  unsigned u = __builtin_bit_cast(unsigned, f);
  u = (u + 0x7FFFu + ((u >> 16) & 1u)) >> 16;  // RNE
  return (u16)u;
}
__device__ __forceinline__ float rcp_(float v) { return __builtin_amdgcn_rcpf(v); }
__device__ __forceinline__ float sig_(float v) { return rcp_(1.f + __expf(-v)); }
__device__ __forceinline__ float tanh_(float v) { return 1.f - 2.f * rcp_(1.f + __expf(2.f * v)); }

#define MFMA16(a, b, c) __builtin_amdgcn_mfma_f32_16x16x32_bf16((a), (b), (c), 0, 0, 0)
#define BAR() asm volatile("s_barrier" ::: "memory")
#define WAITV(n) asm volatile("s_waitcnt vmcnt(" #n ")" ::: "memory")
#define WAITLG() asm volatile("s_waitcnt lgkmcnt(0)" ::: "memory")

__device__ __forceinline__ void gload16(const u16* g, u16* lds) {
#if defined(__HIP_DEVICE_COMPILE__)
  __builtin_amdgcn_global_load_lds(
      (const __attribute__((address_space(1))) unsigned*)g,
      (__attribute__((address_space(3))) unsigned*)lds, 16, 0, 0);
#endif
}

// ---------------- prep kernels ----------------
__global__ void convert_f32_bf16(const float* __restrict__ s, u16* __restrict__ d, int n) {
  int i = (blockIdx.x * blockDim.x + threadIdx.x) * 4;
  if (i + 3 < n) {
    float4 v = *reinterpret_cast<const float4*>(s + i);
    ushort4 o;
    o.x = f2bf(v.x); o.y = f2bf(v.y); o.z = f2bf(v.z); o.w = f2bf(v.w);
    *reinterpret_cast<ushort4*>(d + i) = o;
  }
}

// permuted Whh: p = s*256 + w*64 + f*16 + j  <-  orig row f*512 + s*64 + w*16 + j
__global__ void convert_whh_p(const float* __restrict__ w, u16* __restrict__ d) {
  int p = blockIdx.x;
  int k = threadIdx.x;
  int j = p & 15, f = (p >> 4) & 3, wg = (p >> 6) & 3, s = p >> 8;
  int orig = (f << 9) + (s << 6) + (wg << 4) + j;
  d[p * 512 + k] = f2bf(w[orig * 512 + k]);
}

// augmented-B: Bx[p][0..31] = [Wih[o][0], Wih[o][1], bih[o]+bhh[o], 0...]
__global__ void bx_prep(const float* __restrict__ Wih, const float* __restrict__ bih,
                        const float* __restrict__ bhh, u16* __restrict__ Bx) {
  int p = blockIdx.x * blockDim.x + threadIdx.x;
  if (p >= 2048) return;
  int j = p & 15, f = (p >> 4) & 3, wg = (p >> 6) & 3, s = p >> 8;
  int o = (f << 9) + (s << 6) + (wg << 4) + j;
  u16* row = Bx + p * 32;
  row[0] = f2bf(Wih[o * 2 + 0]);
  row[1] = f2bf(Wih[o * 2 + 1]);
  row[2] = f2bf(bih[o] + bhh[o]);
#pragma unroll
  for (int k = 3; k < 32; ++k) row[k] = 0;
}

// x -> t-major xt[t][n][2] so the step prologue load is coalesced
__global__ void xt_prep(const float* __restrict__ x, float* __restrict__ xt) {
  int id = blockIdx.x * blockDim.x + threadIdx.x;  // 163840 = 20*8192
  if (id >= 163840) return;
  int tt = id >> 13, n = id & 8191;
  float2 v = *reinterpret_cast<const float2*>(x + n * 40 + tt * 2);
  *reinterpret_cast<float2*>(xt + tt * 16384 + n * 2) = v;
}

// h -> bf16; c0 -> fp16 per-thread-linear (epilogue layout); facc(fp16) -> 0
__global__ void init_state(const float* __restrict__ h0, const float* __restrict__ c0,
                           u16* __restrict__ hbf, _Float16* __restrict__ cws,
                           _Float16* __restrict__ facc, int nh, int nacc) {
  int i = blockIdx.x * blockDim.x + threadIdx.x;
  if (i < nh) {
    hbf[i] = f2bf(h0[i]);
    int r = i & 3, mt = (i >> 2) & 7, lane = (i >> 5) & 63, wid = (i >> 11) & 7, bid = i >> 14;
    int s = (bid >> 3) & 7, nb = (bid & 7) * 4 + (bid >> 6);
    int wm = wid >> 2, wn = wid & 3;
    int jl = lane & 15, kg = lane >> 4;
    int n = nb * 256 + wm * 128 + mt * 16 + kg * 4 + r;
    int u = s * 64 + wn * 16 + jl;
    cws[i] = (_Float16)c0[n * 512 + u];
  }
  if (i < nacc) facc[i] = (_Float16)0.f;
}

// ---------------- fused step kernel: 256 blocks x 512 threads, 1 block/CU ----
// LSTM step t: block tile 256n x 256pc (4 gates x 64 u), K=512+aug32, BK=64.
// FC1 (t-1): block tile 128m x 64j, K=1024, BK=128 (8 phases). FC1's tile-0 is
// staged during LSTM phase 7 (parity-1 LDS is free after phase 6's trailing
// barrier) so its HBM latency hides under the activation epilogue.
// XCD-bijective: bid&7 = xcd, nb = (bid&7)*4 + (bid>>6), s = (bid>>3)&7.
__global__ __launch_bounds__(512, 1) void step256(
    const u16* __restrict__ Wp,     // [2048][512] perm bf16
    const u16* __restrict__ Bxg,    // [2048][32] aug B
    const float* __restrict__ xt,   // [20][8192][2] f32 (t-major)
    const u16* __restrict__ hin,    // [8192][512] bf16 = h(t)
    u16* __restrict__ hout,         // h(t+1)
    _Float16* __restrict__ cws,     // c-state fp16 per-thread-linear
    const u16* __restrict__ fc1w,   // [512][20480] bf16
    _Float16* __restrict__ facc,    // [4096][512] fp16
    int t, int doLstm, int doFc1) {
  extern __shared__ char S[];       // 128 KB: p*65536 + {A:0..32K, B:32K..64K}

  const int tid = threadIdx.x;
  const int lane = tid & 63, wid = tid >> 6;
  const int jl = lane & 15, kg = lane >> 4;
  const int bid = blockIdx.x;
  const int s = (bid >> 3) & 7;
  const int nb = (bid & 7) * 4 + (bid >> 6);
  const int n0 = nb * 256;
  const int srow = tid >> 3;
  const int sw = (tid & 7) ^ (srow & 7);
  // FC1 geometry (hoisted so FSTAGE is usable from the LSTM loop)
  const int Fm0 = nb * 128, Fj0 = s * 64;
  const int Fwm = wid >> 1, Fwn = wid & 1;
  const int tf = t - 1;

#define FSTAGE(kt, p)                                                              \
  do {                                                                             \
    const int an_ = (kt) >> 2, hb_ = ((kt) & 3) * 128;                             \
    _Pragma("unroll") for (int kh = 0; kh < 2; ++kh) {                             \
      _Pragma("unroll") for (int q = 0; q < 2; ++q)                                \
        gload16(hin + (2 * (Fm0 + q * 64 + srow) + an_) * 512 + hb_ + kh * 64 + sw * 8, \
                (u16*)(S + (p) * 65536 + kh * 16384 + q * 8192 + wid * 1024));     \
      gload16(fc1w + (Fj0 + srow) * 20480 + an_ * 10240 + tf * 512 + hb_ + kh * 64 + sw * 8, \
              (u16*)(S + (p) * 65536 + 32768 + kh * 8192 + wid * 1024));           \
    }                                                                              \
  } while (0)

  if (doLstm) {
    const int wm = wid >> 2, wn = wid & 3;
    const int u = s * 64 + wn * 16 + jl;
    const int swz0 = (kg ^ (jl & 7)) * 16;
    const int swz1 = ((4 + kg) ^ (jl & 7)) * 16;
    const int aB0 = wm * 16384 + jl * 128 + swz0;
    const int aB1 = wm * 16384 + jl * 128 + swz1;
    const int bB0 = 32768 + wn * 8192 + jl * 128 + swz0;
    const int bB1 = 32768 + wn * 8192 + jl * 128 + swz1;
    const u16* srcA = hin + (n0 + srow) * 512 + sw * 8;
    const u16* srcB = Wp + (s * 256 + srow) * 512 + sw * 8;

    f32x4 acc[8][4];
#pragma unroll
    for (int mt = 0; mt < 8; ++mt)
#pragma unroll
      for (int f = 0; f < 4; ++f) acc[mt][f] = (f32x4){0.f, 0.f, 0.f, 0.f};

    // ---- prologue: x load (coalesced), Bx stage (->p0 B), tile0 stage (->p1) ----
    float2 xv = {0.f, 0.f};
    if (tid < 256) xv = *reinterpret_cast<const float2*>(xt + t * 16384 + (n0 + tid) * 2);
    {
      const int r0 = tid >> 2, ch = tid & 3;
      gload16(Bxg + (s * 256 + 0 * 128 + r0) * 32 + ch * 8, (u16*)(S + 32768 + 0 * 8192 + wid * 1024));
      gload16(Bxg + (s * 256 + 1 * 128 + r0) * 32 + ch * 8, (u16*)(S + 32768 + 1 * 8192 + wid * 1024));
    }
#pragma unroll
    for (int q = 0; q < 4; ++q) {
      gload16(srcA + q * 32768, (u16*)(S + 65536 + q * 8192 + wid * 1024));
      gload16(srcB + q * 32768, (u16*)(S + 65536 + 32768 + q * 8192 + wid * 1024));
    }
    // build Ax rows [x0,x1,1,0...] in p0 A slot
    if (tid < 256) {
      u16 row0[8] = {f2bf(xv.x), f2bf(xv.y), 0x3F80u, 0, 0, 0, 0, 0};
      *reinterpret_cast<uint4*>(S + tid * 64) = *reinterpret_cast<const uint4*>(row0);
      uint4 z = {0u, 0u, 0u, 0u};
      *reinterpret_cast<uint4*>(S + tid * 64 + 16) = z;
      *reinterpret_cast<uint4*>(S + tid * 64 + 32) = z;
      *reinterpret_cast<uint4*>(S + tid * 64 + 48) = z;
    }
    WAITLG();
    WAITV(8);   // Bx (+x) drained; tile0's 8 still in flight
    BAR();
    // ---- aug phase (K=32): gates += x@Wih^T + biases ----
    {
#pragma unroll
      for (int mt = 0; mt < 8; ++mt) {
        bf16x8 a = *reinterpret_cast<const bf16x8*>(S + (wm * 128 + mt * 16 + jl) * 64 + kg * 16);
#pragma unroll
        for (int f = 0; f < 4; ++f) {
          bf16x8 b = *reinterpret_cast<const bf16x8*>(S + 32768 + (wn * 64 + f * 16 + jl) * 64 + kg * 16);
          acc[mt][f] = MFMA16(a, b, acc[mt][f]);
        }
      }
    }
    BAR();

    // ---- main K-loop: 8 tiles, tile kt lives at parity !(kt&1) ----
#define LSTAGE(kt, p)                                                              \
  do {                                                                             \
    _Pragma("unroll") for (int q = 0; q < 4; ++q) {                                \
      gload16(srcA + q * 32768 + (kt) * 64, (u16*)(S + (p) * 65536 + q * 8192 + wid * 1024)); \
      gload16(srcB + q * 32768 + (kt) * 64, (u16*)(S + (p) * 65536 + 32768 + q * 8192 + wid * 1024)); \
    }                                                                              \
  } while (0)
#define LCOMP(p)                                                                   \
  do {                                                                             \
    bf16x8 a0[8], b0[4];                                                           \
    _Pragma("unroll") for (int mt = 0; mt < 8; ++mt)                               \
        a0[mt] = *reinterpret_cast<const bf16x8*>(S + (p) * 65536 + aB0 + mt * 2048); \
    _Pragma("unroll") for (int f = 0; f < 4; ++f)                                  \
        b0[f] = *reinterpret_cast<const bf16x8*>(S + (p) * 65536 + bB0 + f * 2048); \
    _Pragma("unroll") for (int mt = 0; mt < 8; ++mt)                               \
      _Pragma("unroll") for (int f = 0; f < 4; ++f)                                \
        acc[mt][f] = MFMA16(a0[mt], b0[f], acc[mt][f]);                            \
    _Pragma("unroll") for (int mt = 0; mt < 8; ++mt)                               \
        a0[mt] = *reinterpret_cast<const bf16x8*>(S + (p) * 65536 + aB1 + mt * 2048); \
    _Pragma("unroll") for (int f = 0; f < 4; ++f)                                  \
        b0[f] = *reinterpret_cast<const bf16x8*>(S + (p) * 65536 + bB1 + f * 2048); \
    _Pragma("unroll") for (int mt = 0; mt < 8; ++mt)                               \
      _Pragma("unroll") for (int f = 0; f < 4; ++f)                                \
        acc[mt][f] = MFMA16(a0[mt], b0[f], acc[mt][f]);                            \
  } while (0)

#pragma unroll
    for (int kt = 0; kt < 8; ++kt) {
      if (kt < 7) {
        if ((kt + 1) & 1) LSTAGE(kt + 1, 0); else LSTAGE(kt + 1, 1);
        WAITV(8);
      } else {
        // stage FC1 tile0 into p1 (free after phase 6's trailing barrier);
        // WAITV(6) drains LSTM tile7's 8 loads, keeps FC1's 6 in flight
        if (doFc1) { FSTAGE(0, 1); WAITV(6); } else { WAITV(0); }
      }
      BAR();
      if (kt & 1) LCOMP(0); else LCOMP(1);
      BAR();
    }

    // ---- activation epilogue: c fp16 per-thread-linear ----
    _Float16* cbase = cws + ((bid * 8 + wid) * 64 + lane) * 32;
#pragma unroll
    for (int mt = 0; mt < 8; ++mt) {
      f16x4 cv = *reinterpret_cast<f16x4*>(cbase + mt * 4);
      f16x4 cn;
      float hn[4];
#pragma unroll
      for (int r = 0; r < 4; ++r) {
        float iv = sig_(acc[mt][0][r]);
        float fv = sig_(acc[mt][1][r]);
        float gv = tanh_(acc[mt][2][r]);
        float ov = sig_(acc[mt][3][r]);
        float c2 = fv * (float)cv[r] + iv * gv;
        cn[r] = (_Float16)c2;
        hn[r] = ov * tanh_(c2);
      }
      *reinterpret_cast<f16x4*>(cbase + mt * 4) = cn;
#pragma unroll
      for (int r = 0; r < 4; ++r)
        hout[(n0 + wm * 128 + mt * 16 + kg * 4 + r) * 512 + u] = f2bf(hn[r]);
    }
  }

  if (doFc1) {
    // ========== FC1 for t-1: 128m x 64j, K=1024, BK=128, 8 phases ==========
    f32x4 fa[2][2];
#pragma unroll
    for (int a = 0; a < 2; ++a)
#pragma unroll
      for (int b = 0; b < 2; ++b) fa[a][b] = (f32x4){0.f, 0.f, 0.f, 0.f};

#define FCOMP(p)                                                                   \
  do {                                                                             \
    _Pragma("unroll") for (int kk = 0; kk < 4; ++kk) {                             \
      const int kh_ = kk >> 1;                                                     \
      const int cs_ = (((kk & 1) * 4 + kg) ^ (jl & 7)) * 16;                       \
      bf16x8 af[2], bf[2];                                                         \
      _Pragma("unroll") for (int mf = 0; mf < 2; ++mf)                             \
          af[mf] = *reinterpret_cast<const bf16x8*>(                               \
              S + (p) * 65536 + kh_ * 16384 + (Fwm * 32 + mf * 16 + jl) * 128 + cs_); \
      _Pragma("unroll") for (int jf = 0; jf < 2; ++jf)                             \
          bf[jf] = *reinterpret_cast<const bf16x8*>(                               \
              S + (p) * 65536 + 32768 + kh_ * 8192 + (Fwn * 32 + jf * 16 + jl) * 128 + cs_); \
      _Pragma("unroll") for (int mf = 0; mf < 2; ++mf)                             \
        _Pragma("unroll") for (int jf = 0; jf < 2; ++jf)                           \
          fa[mf][jf] = MFMA16(af[mf], bf[jf], fa[mf][jf]);                         \
    }                                                                              \
  } while (0)

    if (!doLstm) FSTAGE(0, 1);   // t==20 tail path stages its own tile0
#pragma unroll
    for (int kt = 0; kt < 8; ++kt) {
      if (kt < 7) {
        if ((kt + 1) & 1) FSTAGE(kt + 1, 0); else FSTAGE(kt + 1, 1);
        WAITV(6);   // drains tile kt (+ epilogue stores); tile kt+1 in flight
      } else {
        WAITV(0);
      }
      BAR();
      if (kt & 1) FCOMP(0); else FCOMP(1);
      BAR();
    }
#pragma unroll
    for (int mf = 0; mf < 2; ++mf)
#pragma unroll
      for (int jf = 0; jf < 2; ++jf) {
        int j = Fj0 + Fwn * 32 + jf * 16 + jl;
#pragma unroll
        for (int r = 0; r < 4; ++r) {
          int m = Fm0 + Fwm * 32 + mf * 16 + kg * 4 + r;
          facc[m * 512 + j] = (_Float16)((float)facc[m * 512 + j] + fa[mf][jf][r]);
        }
      }
  }
}

// ---------------- head: relu(facc + b1) @ fc2^T + b2, sigmoid ----------------
__global__ __launch_bounds__(256) void head_kernel(
    const _Float16* __restrict__ acc, const float* __restrict__ fc1b,
    const float* __restrict__ fc2w, const float* __restrict__ fc2b,
    float* __restrict__ out) {
  int lane = threadIdx.x & 63;
  int row = blockIdx.x * 4 + (threadIdx.x >> 6);
  float sum = 0.f;
#pragma unroll
  for (int j = lane; j < 512; j += 64)
    sum += fmaxf((float)acc[row * 512 + j] + fc1b[j], 0.f) * fc2w[j];
#pragma unroll
  for (int off = 32; off; off >>= 1) sum += __shfl_down(sum, off);
  if (lane == 0) out[row] = 1.f / (1.f + __expf(-(sum + fc2b[0])));
}

extern "C" void kernel_launch(void* const* d_in, const int* in_sizes, int n_in,
                              void* d_out, int out_size, void* d_ws, size_t ws_size,
                              hipStream_t stream) {
  const float* x = (const float*)d_in[0];
  const float* h0 = (const float*)d_in[2];
  const float* c0 = (const float*)d_in[3];
  const float* Wih = (const float*)d_in[4];
  const float* Whh = (const float*)d_in[5];
  const float* bih = (const float*)d_in[6];
  const float* bhh = (const float*)d_in[7];
  const float* fc1w = (const float*)d_in[8];
  const float* fc1b = (const float*)d_in[9];
  const float* fc2w = (const float*)d_in[10];
  const float* fc2b = (const float*)d_in[11];
  float* out = (float*)d_out;

  char* ws = (char*)d_ws;
  const size_t MB = 1 << 20;
  u16* Wp = (u16*)(ws);                        //  2 MB perm Whh
  u16* fc1_bf = (u16*)(ws + 2 * MB);           // 20 MB bf16 fc1w
  u16* hbf0 = (u16*)(ws + 22 * MB);            //  8 MB
  u16* hbf1 = (u16*)(ws + 30 * MB);            //  8 MB
  _Float16* cws = (_Float16*)(ws + 38 * MB);   //  8 MB fp16 c (per-thread-linear)
  _Float16* facc = (_Float16*)(ws + 46 * MB);  //  4 MB fp16 facc
  u16* Bxg = (u16*)(ws + 50 * MB);             // 128 KB
  float* xt = (float*)(ws + 51 * MB);          // 1.25 MB t-major x

  (void)hipFuncSetAttribute(reinterpret_cast<const void*>(step256),
                            hipFuncAttributeMaxDynamicSharedMemorySize, SMEM_BYTES);

  convert_whh_p<<<2048, 512, 0, stream>>>(Whh, Wp);
  bx_prep<<<8, 256, 0, stream>>>(Wih, bih, bhh, Bxg);
  xt_prep<<<640, 256, 0, stream>>>(x, xt);
  convert_f32_bf16<<<10240, 256, 0, stream>>>(fc1w, fc1_bf, 512 * 20480);
  init_state<<<16384, 256, 0, stream>>>(h0, c0, hbf0, cws, facc, 8192 * 512, 4096 * 512);

  u16* hb[2] = {hbf0, hbf1};
  for (int t = 0; t <= TSTEPS; ++t) {
    step256<<<256, 512, SMEM_BYTES, stream>>>(
        Wp, Bxg, xt, hb[t & 1], hb[(t + 1) & 1], cws, fc1_bf, facc,
        t, t < TSTEPS ? 1 : 0, t > 0 ? 1 : 0);
  }
  head_kernel<<<1024, 256, 0, stream>>>(facc, fc1b, fc2w, fc2b, out);
}